// Round 1
// baseline (385.355 us; speedup 1.0000x reference)
//
#include <hip/hip_runtime.h>
#include <stdint.h>

#define B_ 4
#define S_ 1001
#define SP 1008    // padded rows (63 * 16)
#define SPAD 1024  // padded t for PV k-steps (32 * 32)
#define EIN_ 256
#define EOUT_ 64
#define H_ 10
#define NCOL 640   // H*EOUT
#define NCOL3 1920
#define SCW 1048   // sc row stride in bf16 elements (1024 + 24 pad -> conflict-free b128)

typedef short bf16x8 __attribute__((ext_vector_type(8)));
typedef float f32x4 __attribute__((ext_vector_type(4)));

__device__ __forceinline__ unsigned short f2bf(float f) {
  unsigned u = __float_as_uint(f);
  u += 0x7FFFu + ((u >> 16) & 1u);  // RTNE (inputs finite)
  return (unsigned short)(u >> 16);
}
__device__ __forceinline__ float bf2f(unsigned short h) {
  return __uint_as_float(((unsigned)h) << 16);
}

// ---------------- kernel 1: fp32 -> bf16 conversion (x padded, W concat) ----
__global__ __launch_bounds__(256) void convert_kernel(
    const float* __restrict__ x, const float* __restrict__ Wq,
    const float* __restrict__ Wk, const float* __restrict__ Wv,
    unsigned short* __restrict__ xbf, unsigned short* __restrict__ wbf) {
  int i = blockIdx.x * 256 + threadIdx.x;
  const int N1 = B_ * SP * EIN_;   // 1,032,192
  const int N2 = NCOL3 * EIN_;     // 491,520
  if (i < N1) {
    int b = i / (SP * EIN_);
    int rem = i % (SP * EIN_);
    int row = rem / EIN_;
    int e = rem % EIN_;
    float v = (row < S_) ? x[((size_t)(b * S_ + row)) * EIN_ + e] : 0.0f;
    xbf[i] = f2bf(v);
  } else if (i < N1 + N2) {
    int j = i - N1;
    int col = j / EIN_;
    int e = j % EIN_;
    int mat = col / NCOL;
    int hcol = col % NCOL;
    const float* W = (mat == 0) ? Wq : (mat == 1) ? Wk : Wv;
    wbf[j] = f2bf(W[(size_t)hcol * EIN_ + e]);
  }
}

// ---------------- kernel 2: projection GEMM (MFMA bf16) ----------------
__global__ __launch_bounds__(256) void proj_kernel(
    const unsigned short* __restrict__ xbf, const unsigned short* __restrict__ wbf,
    const float* __restrict__ bq, const float* __restrict__ bk,
    const float* __restrict__ bv, unsigned short* __restrict__ qbf,
    unsigned short* __restrict__ kbf, unsigned short* __restrict__ vrow) {
  int tid = threadIdx.x;
  int wv_ = tid >> 6;
  int l = tid & 63;
  int qd = l >> 4;
  int c = l & 15;
  int bid = blockIdx.x;
  int b = bid / 63;
  int tile = bid % 63;
  int s0 = tile * 16;

  bf16x8 af[8];
  const unsigned short* xrowp = xbf + (size_t)(b * SP + s0 + c) * EIN_;
#pragma unroll
  for (int ks = 0; ks < 8; ++ks)
    af[ks] = *(const bf16x8*)(xrowp + ks * 32 + qd * 8);

  for (int nt = wv_; nt < 120; nt += 4) {
    int col0 = nt * 16;
    f32x4 acc = {0.f, 0.f, 0.f, 0.f};
    const unsigned short* wrow = wbf + (size_t)(col0 + c) * EIN_;
#pragma unroll
    for (int ks = 0; ks < 8; ++ks) {
      bf16x8 bfg = *(const bf16x8*)(wrow + ks * 32 + qd * 8);
      acc = __builtin_amdgcn_mfma_f32_16x16x32_bf16(af[ks], bfg, acc, 0, 0, 0);
    }
    int col = col0 + c;
    int mat = col / NCOL;
    int hcol = col % NCOL;
    int hh = hcol >> 6;
    int o = hcol & 63;
    const float* bias = (mat == 0) ? bq : (mat == 1) ? bk : bv;
    float bb = bias[hcol];
    unsigned short* dst = (mat == 0) ? qbf : (mat == 1) ? kbf : vrow;
    size_t base = ((size_t)(b * H_ + hh)) * SPAD * EOUT_ + o;
#pragma unroll
    for (int i = 0; i < 4; ++i) {
      int srow = s0 + qd * 4 + i;
      float v = (srow < S_) ? (acc[i] + bb) : 0.0f;  // zero pad rows
      dst[base + (size_t)srow * EOUT_] = f2bf(v);
    }
  }
}

// ---------------- kernel 3: v [t][o] -> vT [o][t] ----------------
__global__ __launch_bounds__(256) void transpose_v(
    const unsigned short* __restrict__ vrow, unsigned short* __restrict__ vT) {
  __shared__ unsigned short tl[64 * 65];
  int bid = blockIdx.x;
  int bh = bid >> 4;
  int t0 = (bid & 15) * 64;
  int tid = threadIdx.x;
#pragma unroll
  for (int i = 0; i < 16; ++i) {
    int idx = i * 256 + tid;
    int o = idx & 63;
    int t_l = idx >> 6;
    tl[o * 65 + t_l] = vrow[((size_t)bh * SPAD + t0 + t_l) * EOUT_ + o];
  }
  __syncthreads();
#pragma unroll
  for (int i = 0; i < 16; ++i) {
    int idx = i * 256 + tid;
    int t_l = idx & 63;
    int o = idx >> 6;
    vT[((size_t)bh * EOUT_ + o) * SPAD + t0 + t_l] = tl[o * 65 + t_l];
  }
}

// ---------------- kernel 4: fused attention, all heads per block ----------------
__global__ __launch_bounds__(256) void attn_kernel(
    const unsigned short* __restrict__ qbf, const unsigned short* __restrict__ kbf,
    const unsigned short* __restrict__ vT, const float* __restrict__ mask,
    float* __restrict__ out) {
  __shared__ unsigned short sc[16 * SCW];
  __shared__ float maxpart[64];
  __shared__ float normpart[64];
  __shared__ float rs[16];

  int tid = threadIdx.x;
  int wv_ = tid >> 6;
  int l = tid & 63;
  int qd = l >> 4;
  int c = l & 15;
  int bid = blockIdx.x;
  int b = bid / 63;
  int tile = bid % 63;
  int s0 = tile * 16;

  float* concat = out;                          // [B,S,640]
  float* wsum = out + (size_t)B_ * S_ * NCOL;   // [B,S,S]

  float wacc[64];
#pragma unroll
  for (int i = 0; i < 64; ++i) wacc[i] = 0.0f;

  int r = c;
  int srow_r = s0 + r;
  int srow_c = srow_r < S_ ? srow_r : S_ - 1;
  const float* mrow = mask + (size_t)srow_c * S_;

  for (int h = 0; h < H_; ++h) {
    size_t bh = (size_t)(b * H_ + h);
    const unsigned short* qb = qbf + bh * SPAD * EOUT_;
    const unsigned short* kb = kbf + bh * SPAD * EOUT_;
    const unsigned short* vb = vT + bh * EOUT_ * SPAD;

    // ---- scores = (Q K^T)/16, bf16 into LDS; track fp32 row max ----
    bf16x8 aq0 = *(const bf16x8*)(qb + (size_t)(s0 + c) * EOUT_ + qd * 8);
    bf16x8 aq1 = *(const bf16x8*)(qb + (size_t)(s0 + c) * EOUT_ + 32 + qd * 8);
    float mpart[4] = {-1e30f, -1e30f, -1e30f, -1e30f};
    for (int tt = wv_; tt < 63; tt += 4) {
      int t0 = tt * 16;
      f32x4 acc = {0.f, 0.f, 0.f, 0.f};
      const unsigned short* krow = kb + (size_t)(t0 + c) * EOUT_ + qd * 8;
      acc = __builtin_amdgcn_mfma_f32_16x16x32_bf16(aq0, *(const bf16x8*)krow, acc, 0, 0, 0);
      acc = __builtin_amdgcn_mfma_f32_16x16x32_bf16(aq1, *(const bf16x8*)(krow + 32), acc, 0, 0, 0);
#pragma unroll
      for (int i = 0; i < 4; ++i) {
        float v = acc[i] * 0.0625f;
        mpart[i] = fmaxf(mpart[i], v);
        sc[(qd * 4 + i) * SCW + t0 + c] = f2bf(v);
      }
    }
#pragma unroll
    for (int i = 0; i < 4; ++i) {
      float m = mpart[i];
      m = fmaxf(m, __shfl_xor(m, 1));
      m = fmaxf(m, __shfl_xor(m, 2));
      m = fmaxf(m, __shfl_xor(m, 4));
      m = fmaxf(m, __shfl_xor(m, 8));
      if (c == 0) maxpart[wv_ * 16 + qd * 4 + i] = m;
    }
    __syncthreads();

    // ---- l = exp(s - m) * mask (unnormalized w), accumulate sum(l^2) ----
    float m_r = fmaxf(fmaxf(maxpart[r], maxpart[16 + r]),
                      fmaxf(maxpart[32 + r], maxpart[48 + r]));
    float nacc = 0.0f;
#pragma unroll
    for (int si = 0; si < 8; ++si) {
      int tb = (wv_ * 8 + si) * 32 + qd * 8;
      unsigned short* sp = &sc[r * SCW + tb];
      bf16x8 sv = *(bf16x8*)sp;
      bf16x8 lv;
#pragma unroll
      for (int j = 0; j < 8; ++j) {
        int t = tb + j;
        float s = bf2f((unsigned short)sv[j]);
        float e = __expf(s - m_r);
        float lval = (t < S_) ? e * mrow[t] : 0.0f;
        nacc += lval * lval;
        lv[j] = (short)f2bf(lval);
      }
      *(bf16x8*)sp = lv;
    }
    nacc += __shfl_xor(nacc, 16);
    nacc += __shfl_xor(nacc, 32);
    if (qd == 0) normpart[wv_ * 16 + r] = nacc;
    __syncthreads();
    if (tid < 16) {
      float s = normpart[tid] + normpart[16 + tid] + normpart[32 + tid] +
                normpart[48 + tid];
      rs[tid] = 1.0f / fmaxf(sqrtf(s), 1e-12f);
    }
    __syncthreads();

    // ---- weights_sum accumulate in registers ----
    float rsr = rs[r];
#pragma unroll
    for (int si = 0; si < 8; ++si) {
      int tb = (wv_ * 8 + si) * 32 + qd * 8;
      bf16x8 sv = *(const bf16x8*)&sc[r * SCW + tb];
#pragma unroll
      for (int j = 0; j < 8; ++j)
        wacc[si * 8 + j] += bf2f((unsigned short)sv[j]) * rsr;
    }

    // ---- out = (l V) * rsqrt(row) ; wave wv_ owns o in [16*wv_, 16*wv_+16) ----
    f32x4 oacc = {0.f, 0.f, 0.f, 0.f};
    const unsigned short* vrow_ = vb + (size_t)(wv_ * 16 + c) * SPAD;
#pragma unroll
    for (int kstep = 0; kstep < 32; ++kstep) {
      bf16x8 afr = *(const bf16x8*)&sc[c * SCW + kstep * 32 + qd * 8];
      bf16x8 bfr = *(const bf16x8*)(vrow_ + kstep * 32 + qd * 8);
      oacc = __builtin_amdgcn_mfma_f32_16x16x32_bf16(afr, bfr, oacc, 0, 0, 0);
    }
#pragma unroll
    for (int i = 0; i < 4; ++i) {
      int row = qd * 4 + i;
      int srow = s0 + row;
      if (srow < S_)
        concat[((size_t)(b * S_) + srow) * NCOL + h * EOUT_ + wv_ * 16 + c] =
            oacc[i] * rs[row];
    }
    __syncthreads();  // protect sc before next head's score writes
  }

  // ---- weights_sum store ----
  if (srow_r < S_) {
    float* wrow = wsum + ((size_t)b * S_ + srow_r) * S_;
#pragma unroll
    for (int si = 0; si < 8; ++si) {
      int tb = (wv_ * 8 + si) * 32 + qd * 8;
#pragma unroll
      for (int j = 0; j < 8; ++j) {
        int t = tb + j;
        if (t < S_) wrow[t] = wacc[si * 8 + j];
      }
    }
  }
}

extern "C" void kernel_launch(void* const* d_in, const int* in_sizes, int n_in,
                              void* d_out, int out_size, void* d_ws, size_t ws_size,
                              hipStream_t stream) {
  const float* x = (const float*)d_in[0];
  const float* mask = (const float*)d_in[1];
  const float* Wq = (const float*)d_in[2];
  const float* bq = (const float*)d_in[3];
  const float* Wk = (const float*)d_in[4];
  const float* bk = (const float*)d_in[5];
  const float* Wv = (const float*)d_in[6];
  const float* bv = (const float*)d_in[7];
  float* out = (float*)d_out;

  char* ws = (char*)d_ws;
  if (ws_size < 24018944) return;  // fail cleanly rather than OOB
  unsigned short* xbf  = (unsigned short*)ws;              // 2,064,384 B
  unsigned short* wbf  = (unsigned short*)(ws + 2064384);  //   983,040 B
  unsigned short* qbf  = (unsigned short*)(ws + 3047424);  // 5,242,880 B
  unsigned short* kbf  = (unsigned short*)(ws + 8290304);  // 5,242,880 B
  unsigned short* vrow = (unsigned short*)(ws + 13533184); // 5,242,880 B
  unsigned short* vT   = (unsigned short*)(ws + 18776064); // 5,242,880 B

  convert_kernel<<<5952, 256, 0, stream>>>(x, Wq, Wk, Wv, xbf, wbf);
  proj_kernel<<<252, 256, 0, stream>>>(xbf, wbf, bq, bk, bv, qbf, kbf, vrow);
  transpose_v<<<640, 256, 0, stream>>>(vrow, vT);
  attn_kernel<<<252, 256, 0, stream>>>(qbf, kbf, vT, mask, out);
}

// Round 3
// 297.130 us; speedup vs baseline: 1.2969x; 1.2969x over previous
//
#include <hip/hip_runtime.h>
#include <stdint.h>

#define B_ 4
#define S_ 1001
#define SP 1008    // padded rows (63 * 16)
#define SPAD 1024  // padded t dimension (32 * 32)
#define EIN_ 256
#define EOUT_ 64
#define H_ 10
#define NCOL 640   // H*EOUT
#define NCOL3 1920
#define SCW 1048   // sc row stride in bf16 (1024 + 24 pad -> 2-way-free b128 frag reads)

typedef short bf16x8 __attribute__((ext_vector_type(8)));
typedef short bf16x4 __attribute__((ext_vector_type(4)));
typedef float f32x4 __attribute__((ext_vector_type(4)));

__device__ __forceinline__ unsigned short f2bf(float f) {
  unsigned u = __float_as_uint(f);
  u += 0x7FFFu + ((u >> 16) & 1u);  // RTNE (inputs finite)
  return (unsigned short)(u >> 16);
}
__device__ __forceinline__ float bf2f(unsigned short h) {
  return __uint_as_float(((unsigned)h) << 16);
}

// ---------------- kernel 1: fp32 -> bf16 conversion (x padded, W concat) ----
__global__ __launch_bounds__(256) void convert_kernel(
    const float* __restrict__ x, const float* __restrict__ Wq,
    const float* __restrict__ Wk, const float* __restrict__ Wv,
    unsigned short* __restrict__ xbf, unsigned short* __restrict__ wbf) {
  int i = blockIdx.x * 256 + threadIdx.x;
  const int N1 = B_ * SP * EIN_;   // 1,032,192
  const int N2 = NCOL3 * EIN_;     // 491,520
  if (i < N1) {
    int b = i / (SP * EIN_);
    int rem = i % (SP * EIN_);
    int row = rem / EIN_;
    int e = rem % EIN_;
    float v = (row < S_) ? x[((size_t)(b * S_ + row)) * EIN_ + e] : 0.0f;
    xbf[i] = f2bf(v);
  } else if (i < N1 + N2) {
    int j = i - N1;
    int col = j / EIN_;
    int e = j % EIN_;
    int mat = col / NCOL;
    int hcol = col % NCOL;
    const float* W = (mat == 0) ? Wq : (mat == 1) ? Wk : Wv;
    wbf[j] = f2bf(W[(size_t)hcol * EIN_ + e]);
  }
}

// ---------------- kernel 2: projection GEMM (MFMA bf16), 6-way N split ------
__global__ __launch_bounds__(256) void proj_kernel(
    const unsigned short* __restrict__ xbf, const unsigned short* __restrict__ wbf,
    const float* __restrict__ bq, const float* __restrict__ bk,
    const float* __restrict__ bv, unsigned short* __restrict__ qbf,
    unsigned short* __restrict__ kbf, unsigned short* __restrict__ vrow) {
  int tid = threadIdx.x;
  int wv_ = tid >> 6;
  int l = tid & 63;
  int qd = l >> 4;
  int c = l & 15;
  int bid = blockIdx.x;
  int g = bid % 6;
  int t2 = bid / 6;
  int b = t2 / 63;
  int tile = t2 % 63;
  int s0 = tile * 16;

  bf16x8 af[8];
  const unsigned short* xrowp = xbf + (size_t)(b * SP + s0 + c) * EIN_;
#pragma unroll
  for (int ks = 0; ks < 8; ++ks)
    af[ks] = *(const bf16x8*)(xrowp + ks * 32 + qd * 8);

  for (int nt = g * 20 + wv_; nt < g * 20 + 20; nt += 4) {
    int col0 = nt * 16;
    f32x4 acc = {0.f, 0.f, 0.f, 0.f};
    const unsigned short* wrow = wbf + (size_t)(col0 + c) * EIN_;
#pragma unroll
    for (int ks = 0; ks < 8; ++ks) {
      bf16x8 bfg = *(const bf16x8*)(wrow + ks * 32 + qd * 8);
      acc = __builtin_amdgcn_mfma_f32_16x16x32_bf16(af[ks], bfg, acc, 0, 0, 0);
    }
    int col = col0 + c;
    int mat = col / NCOL;
    int hcol = col % NCOL;
    int hh = hcol >> 6;
    int o = hcol & 63;
    const float* bias = (mat == 0) ? bq : (mat == 1) ? bk : bv;
    float bb = bias[hcol];
    unsigned short* dst = (mat == 0) ? qbf : (mat == 1) ? kbf : vrow;
    size_t base = ((size_t)(b * H_ + hh)) * SPAD * EOUT_ + o;
#pragma unroll
    for (int i = 0; i < 4; ++i) {
      int srow = s0 + qd * 4 + i;
      float v = (srow < S_) ? (acc[i] + bb) : 0.0f;  // zero pad rows
      dst[base + (size_t)srow * EOUT_] = f2bf(v);
    }
  }
}

// ---------------- kernel 3: v [t][o] -> vT [o][t] ----------------
__global__ __launch_bounds__(256) void transpose_v(
    const unsigned short* __restrict__ vrow, unsigned short* __restrict__ vT) {
  __shared__ unsigned short tl[64 * 65];
  int bid = blockIdx.x;
  int bh = bid >> 4;
  int t0 = (bid & 15) * 64;
  int tid = threadIdx.x;
#pragma unroll
  for (int i = 0; i < 16; ++i) {
    int idx = i * 256 + tid;
    int o = idx & 63;
    int t_l = idx >> 6;
    tl[o * 65 + t_l] = vrow[((size_t)bh * SPAD + t0 + t_l) * EOUT_ + o];
  }
  __syncthreads();
#pragma unroll
  for (int i = 0; i < 16; ++i) {
    int idx = i * 256 + tid;
    int t_l = idx & 63;
    int o = idx >> 6;
    vT[((size_t)bh * EOUT_ + o) * SPAD + t0 + t_l] = tl[o * 65 + t_l];
  }
}

// ---------------- kernel 4: attention, one (b,h,tile) per block ----------------
template <bool ATOMIC>
__global__ __launch_bounds__(256) void attn_kernel(
    const unsigned short* __restrict__ qbf, const unsigned short* __restrict__ kbf,
    const unsigned short* __restrict__ vT, const float* __restrict__ mask,
    unsigned short* __restrict__ whbf, float* __restrict__ rsbuf,
    float* __restrict__ out) {
  __shared__ unsigned short sc[16 * SCW];
  __shared__ float normpart[64];
  __shared__ float rs[16];

  int tid = threadIdx.x;
  int wv_ = tid >> 6;
  int l = tid & 63;
  int qd = l >> 4;
  int c = l & 15;
  int bid = blockIdx.x;
  int b = bid / (H_ * 63);
  int rem = bid % (H_ * 63);
  int h = rem / 63;
  int tile = rem % 63;
  int s0 = tile * 16;

  float* concat = out;                          // [B,S,640]
  float* wsum = out + (size_t)B_ * S_ * NCOL;   // [B,S,S]

  size_t bh = (size_t)(b * H_ + h);
  const unsigned short* qb = qbf + bh * SPAD * EOUT_;
  const unsigned short* kb = kbf + bh * SPAD * EOUT_;
  const unsigned short* vb = vT + bh * EOUT_ * SPAD;

  int r = c;
  int srow_r = s0 + r;
  int srow_c = srow_r < S_ ? srow_r : S_ - 1;
  const float* mrow = mask + (size_t)srow_c * S_;

  // ---- phase A: scores = (Q K^T)/16, bf16 into LDS (no max shift needed:
  // scores are O(0.1); the shift cancels exactly in L2-normalize) ----
  bf16x8 aq0 = *(const bf16x8*)(qb + (size_t)(s0 + c) * EOUT_ + qd * 8);
  bf16x8 aq1 = *(const bf16x8*)(qb + (size_t)(s0 + c) * EOUT_ + 32 + qd * 8);
  for (int tt = wv_; tt < 63; tt += 4) {
    int t0 = tt * 16;
    f32x4 acc = {0.f, 0.f, 0.f, 0.f};
    const unsigned short* krow = kb + (size_t)(t0 + c) * EOUT_ + qd * 8;
    acc = __builtin_amdgcn_mfma_f32_16x16x32_bf16(aq0, *(const bf16x8*)krow, acc, 0, 0, 0);
    acc = __builtin_amdgcn_mfma_f32_16x16x32_bf16(aq1, *(const bf16x8*)(krow + 32), acc, 0, 0, 0);
#pragma unroll
    for (int i = 0; i < 4; ++i)
      sc[(qd * 4 + i) * SCW + t0 + c] = f2bf(acc[i] * 0.0625f);
  }
  __syncthreads();

  // ---- phase B: l = exp(s) * mask (unnormalized), sum(l^2) per row ----
  float nacc = 0.0f;
#pragma unroll
  for (int si = 0; si < 8; ++si) {
    int tb = (wv_ * 8 + si) * 32 + qd * 8;
    unsigned short* sp = &sc[r * SCW + tb];
    bf16x8 sv = *(bf16x8*)sp;
    bf16x8 lv;
#pragma unroll
    for (int j = 0; j < 8; ++j) {
      int t = tb + j;
      float s = bf2f((unsigned short)sv[j]);
      float e = __expf(s);
      float lval = (t < S_) ? e * mrow[t] : 0.0f;
      nacc += lval * lval;
      lv[j] = (short)f2bf(lval);
    }
    *(bf16x8*)sp = lv;
  }
  nacc += __shfl_xor(nacc, 16);
  nacc += __shfl_xor(nacc, 32);
  if (qd == 0) normpart[wv_ * 16 + r] = nacc;
  __syncthreads();
  if (tid < 16) {
    float s = normpart[tid] + normpart[16 + tid] + normpart[32 + tid] +
              normpart[48 + tid];
    rs[tid] = 1.0f / fmaxf(sqrtf(s), 1e-12f);
  }
  __syncthreads();

  // ---- phase C: export l (and rs) for the head-reduction ----
  if (!ATOMIC) {
    size_t base = ((size_t)bh * 63 + tile) * (16 * 1024);
#pragma unroll
    for (int i = 0; i < 8; ++i) {
      int f = i * 2048 + tid * 8;
      int row = f >> 10;
      int col = f & 1023;
      *(bf16x8*)(whbf + base + f) = *(const bf16x8*)&sc[row * SCW + col];
    }
    if (tid < 16) rsbuf[((size_t)bh * 63 + tile) * 16 + tid] = rs[tid];
  } else {
#pragma unroll
    for (int i = 0; i < 8; ++i) {
      int f = i * 2048 + tid * 8;
      int row = f >> 10;
      int col0 = f & 1023;
      int srow = s0 + row;
      if (srow < S_) {
        float rsr = rs[row];
        bf16x8 sv = *(const bf16x8*)&sc[row * SCW + col0];
        float* wrow = wsum + ((size_t)b * S_ + srow) * S_;
#pragma unroll
        for (int j = 0; j < 8; ++j) {
          int t = col0 + j;
          if (t < S_) atomicAdd(&wrow[t], bf2f((unsigned short)sv[j]) * rsr);
        }
      }
    }
  }

  // ---- phase D: out = (l V) * rsqrt(row); wave wv_ owns o in [16wv,16wv+16) ----
  f32x4 oacc = {0.f, 0.f, 0.f, 0.f};
  const unsigned short* vrow_ = vb + (size_t)(wv_ * 16 + c) * SPAD;
#pragma unroll
  for (int kstep = 0; kstep < 32; ++kstep) {
    bf16x8 afr = *(const bf16x8*)&sc[c * SCW + kstep * 32 + qd * 8];
    bf16x8 bfr = *(const bf16x8*)(vrow_ + kstep * 32 + qd * 8);
    oacc = __builtin_amdgcn_mfma_f32_16x16x32_bf16(afr, bfr, oacc, 0, 0, 0);
  }
#pragma unroll
  for (int i = 0; i < 4; ++i) {
    int row = qd * 4 + i;
    int srow = s0 + row;
    if (srow < S_)
      concat[((size_t)(b * S_) + srow) * NCOL + h * EOUT_ + wv_ * 16 + c] =
          oacc[i] * rs[row];
  }
}

// ---------------- kernel 5: weights_sum = sum_h rs * l ----------------
__global__ __launch_bounds__(256) void reduce_kernel(
    const unsigned short* __restrict__ whbf, const float* __restrict__ rsbuf,
    float* __restrict__ out) {
  int bid = blockIdx.x;
  int b = bid / SP;
  int s = bid % SP;
  if (s >= S_) return;
  int tile = s >> 4;
  int row = s & 15;
  int tid = threadIdx.x;
  int col0 = tid * 4;
  float a0 = 0.f, a1 = 0.f, a2 = 0.f, a3 = 0.f;
#pragma unroll
  for (int h = 0; h < H_; ++h) {
    size_t idx = (size_t)((b * H_ + h) * 63 + tile);
    float rsr = rsbuf[idx * 16 + row];
    bf16x4 lv = *(const bf16x4*)(whbf + idx * (16 * 1024) + row * 1024 + col0);
    a0 += rsr * bf2f((unsigned short)lv[0]);
    a1 += rsr * bf2f((unsigned short)lv[1]);
    a2 += rsr * bf2f((unsigned short)lv[2]);
    a3 += rsr * bf2f((unsigned short)lv[3]);
  }
  float* wsum = out + (size_t)B_ * S_ * NCOL;
  float* wrow = wsum + ((size_t)b * S_ + s) * S_;
  if (col0 + 3 < S_) {
    wrow[col0] = a0; wrow[col0 + 1] = a1; wrow[col0 + 2] = a2; wrow[col0 + 3] = a3;
  } else {
    if (col0 < S_) wrow[col0] = a0;
    if (col0 + 1 < S_) wrow[col0 + 1] = a1;
    if (col0 + 2 < S_) wrow[col0 + 2] = a2;
    if (col0 + 3 < S_) wrow[col0 + 3] = a3;
  }
}

// ---------------- kernel 6: zero wsum (atomic fallback path only) ----------
__global__ __launch_bounds__(256) void zero_wsum(float* __restrict__ out) {
  size_t idx = (size_t)blockIdx.x * 256 + threadIdx.x;
  const size_t n = (size_t)B_ * S_ * S_;
  if (idx < n) out[(size_t)B_ * S_ * NCOL + idx] = 0.0f;
}

extern "C" void kernel_launch(void* const* d_in, const int* in_sizes, int n_in,
                              void* d_out, int out_size, void* d_ws, size_t ws_size,
                              hipStream_t stream) {
  const float* x = (const float*)d_in[0];
  const float* mask = (const float*)d_in[1];
  const float* Wq = (const float*)d_in[2];
  const float* bq = (const float*)d_in[3];
  const float* Wk = (const float*)d_in[4];
  const float* bk = (const float*)d_in[5];
  const float* Wv = (const float*)d_in[6];
  const float* bv = (const float*)d_in[7];
  float* out = (float*)d_out;

  char* ws = (char*)d_ws;
  const size_t NEED_BASE = 24018944;     // xbf..vT
  const size_t NEED_FULL = 106755584;    // + whbf (82.6MB) + rsbuf
  if (ws_size < NEED_BASE) return;       // fail cleanly rather than OOB
  unsigned short* xbf  = (unsigned short*)ws;              // 2,064,384 B
  unsigned short* wbf  = (unsigned short*)(ws + 2064384);  //   983,040 B
  unsigned short* qbf  = (unsigned short*)(ws + 3047424);  // 5,242,880 B
  unsigned short* kbf  = (unsigned short*)(ws + 8290304);  // 5,242,880 B
  unsigned short* vrow = (unsigned short*)(ws + 13533184); // 5,242,880 B
  unsigned short* vT   = (unsigned short*)(ws + 18776064); // 5,242,880 B
  unsigned short* whbf = (unsigned short*)(ws + 24018944); // 82,575,360 B
  float*          rsbuf = (float*)(ws + 106594304);        //   161,280 B

  convert_kernel<<<5952, 256, 0, stream>>>(x, Wq, Wk, Wv, xbf, wbf);
  proj_kernel<<<1512, 256, 0, stream>>>(xbf, wbf, bq, bk, bv, qbf, kbf, vrow);
  transpose_v<<<640, 256, 0, stream>>>(vrow, vT);

  if (ws_size >= NEED_FULL) {
    attn_kernel<false><<<2520, 256, 0, stream>>>(qbf, kbf, vT, mask, whbf, rsbuf, out);
    reduce_kernel<<<B_ * SP, 256, 0, stream>>>(whbf, rsbuf, out);
  } else {
    zero_wsum<<<15657, 256, 0, stream>>>(out);
    attn_kernel<true><<<2520, 256, 0, stream>>>(qbf, kbf, vT, mask, whbf, rsbuf, out);
  }
}

// Round 4
// 261.038 us; speedup vs baseline: 1.4762x; 1.1383x over previous
//
#include <hip/hip_runtime.h>
#include <stdint.h>

#define B_ 4
#define S_ 1001
#define SP 1008    // padded rows (63 * 16)
#define SPAD 1024  // padded t dimension (32 * 32)
#define EIN_ 256
#define EOUT_ 64
#define H_ 10
#define NCOL 640   // H*EOUT
#define NCOL3 1920
#define SCW 1048   // sc row stride in bf16 (1024 + 24 pad)

typedef short bf16x8 __attribute__((ext_vector_type(8)));
typedef short bf16x4 __attribute__((ext_vector_type(4)));
typedef float f32x4 __attribute__((ext_vector_type(4)));

__device__ __forceinline__ unsigned short f2bf(float f) {
  unsigned u = __float_as_uint(f);
  u += 0x7FFFu + ((u >> 16) & 1u);  // RTNE (inputs finite)
  return (unsigned short)(u >> 16);
}
__device__ __forceinline__ float bf2f(unsigned short h) {
  return __uint_as_float(((unsigned)h) << 16);
}

// ---- kernel 1: fp32 -> bf16 (x padded, W concat) + mask zero-padded fp32 ----
__global__ __launch_bounds__(256) void convert_kernel(
    const float* __restrict__ x, const float* __restrict__ Wq,
    const float* __restrict__ Wk, const float* __restrict__ Wv,
    const float* __restrict__ mask, unsigned short* __restrict__ xbf,
    unsigned short* __restrict__ wbf, float* __restrict__ mpad) {
  int i = blockIdx.x * 256 + threadIdx.x;
  const int N1 = B_ * SP * EIN_;   // 1,032,192
  const int N2 = NCOL3 * EIN_;     // 491,520
  const int N3 = SP * SPAD;        // 1,032,192
  if (i < N1) {
    int b = i / (SP * EIN_);
    int rem = i % (SP * EIN_);
    int row = rem / EIN_;
    int e = rem % EIN_;
    float v = (row < S_) ? x[((size_t)(b * S_ + row)) * EIN_ + e] : 0.0f;
    xbf[i] = f2bf(v);
  } else if (i < N1 + N2) {
    int j = i - N1;
    int col = j / EIN_;
    int e = j % EIN_;
    int mat = col / NCOL;
    int hcol = col % NCOL;
    const float* W = (mat == 0) ? Wq : (mat == 1) ? Wk : Wv;
    wbf[j] = f2bf(W[(size_t)hcol * EIN_ + e]);
  } else if (i < N1 + N2 + N3) {
    int j = i - N1 - N2;
    int row = j >> 10;
    int col = j & 1023;
    mpad[j] = (row < S_ && col < S_) ? mask[(size_t)row * S_ + col] : 0.0f;
  }
}

// ---------------- kernel 2: projection GEMM (MFMA bf16), 6-way N split ------
__global__ __launch_bounds__(256) void proj_kernel(
    const unsigned short* __restrict__ xbf, const unsigned short* __restrict__ wbf,
    const float* __restrict__ bq, const float* __restrict__ bk,
    const float* __restrict__ bv, unsigned short* __restrict__ qbf,
    unsigned short* __restrict__ kbf, unsigned short* __restrict__ vrow) {
  int tid = threadIdx.x;
  int wv_ = tid >> 6;
  int l = tid & 63;
  int qd = l >> 4;
  int c = l & 15;
  int bid = blockIdx.x;
  int g = bid % 6;
  int t2 = bid / 6;
  int b = t2 / 63;
  int tile = t2 % 63;
  int s0 = tile * 16;

  bf16x8 af[8];
  const unsigned short* xrowp = xbf + (size_t)(b * SP + s0 + c) * EIN_;
#pragma unroll
  for (int ks = 0; ks < 8; ++ks)
    af[ks] = *(const bf16x8*)(xrowp + ks * 32 + qd * 8);

  for (int nt = g * 20 + wv_; nt < g * 20 + 20; nt += 4) {
    int col0 = nt * 16;
    f32x4 acc = {0.f, 0.f, 0.f, 0.f};
    const unsigned short* wrow = wbf + (size_t)(col0 + c) * EIN_;
#pragma unroll
    for (int ks = 0; ks < 8; ++ks) {
      bf16x8 bfg = *(const bf16x8*)(wrow + ks * 32 + qd * 8);
      acc = __builtin_amdgcn_mfma_f32_16x16x32_bf16(af[ks], bfg, acc, 0, 0, 0);
    }
    int col = col0 + c;
    int mat = col / NCOL;
    int hcol = col % NCOL;
    int hh = hcol >> 6;
    int o = hcol & 63;
    const float* bias = (mat == 0) ? bq : (mat == 1) ? bk : bv;
    float bb = bias[hcol];
    unsigned short* dst = (mat == 0) ? qbf : (mat == 1) ? kbf : vrow;
    size_t base = ((size_t)(b * H_ + hh)) * SPAD * EOUT_ + o;
#pragma unroll
    for (int i = 0; i < 4; ++i) {
      int srow = s0 + qd * 4 + i;
      float v = (srow < S_) ? (acc[i] + bb) : 0.0f;  // zero pad rows
      dst[base + (size_t)srow * EOUT_] = f2bf(v);
    }
  }
}

// ---------------- kernel 3: v [t][o] -> vT [o][t] ----------------
__global__ __launch_bounds__(256) void transpose_v(
    const unsigned short* __restrict__ vrow, unsigned short* __restrict__ vT) {
  __shared__ unsigned short tl[64 * 65];
  int bid = blockIdx.x;
  int bh = bid >> 4;
  int t0 = (bid & 15) * 64;
  int tid = threadIdx.x;
#pragma unroll
  for (int i = 0; i < 16; ++i) {
    int idx = i * 256 + tid;
    int o = idx & 63;
    int t_l = idx >> 6;
    tl[o * 65 + t_l] = vrow[((size_t)bh * SPAD + t0 + t_l) * EOUT_ + o];
  }
  __syncthreads();
#pragma unroll
  for (int i = 0; i < 16; ++i) {
    int idx = i * 256 + tid;
    int t_l = idx & 63;
    int o = idx >> 6;
    vT[((size_t)bh * EOUT_ + o) * SPAD + t0 + t_l] = tl[o * 65 + t_l];
  }
}

// ---------------- kernel 4: attention (concat out + rs export) ----------------
__global__ __launch_bounds__(256) void attn_kernel(
    const unsigned short* __restrict__ qbf, const unsigned short* __restrict__ kbf,
    const unsigned short* __restrict__ vT, const float* __restrict__ mpad,
    float* __restrict__ rsbuf, float* __restrict__ out) {
  __shared__ unsigned short sc[16 * SCW];
  __shared__ float rs[16];

  int tid = threadIdx.x;
  int wv_ = tid >> 6;
  int l = tid & 63;
  int qd = l >> 4;
  int c = l & 15;
  int bid = blockIdx.x;
  int b = bid / (H_ * 63);
  int rem = bid % (H_ * 63);
  int h = rem / 63;
  int tile = rem % 63;
  int s0 = tile * 16;

  if (tid < 16) rs[tid] = 0.0f;

  float* concat = out;  // [B,S,640]

  size_t bh = (size_t)(b * H_ + h);
  const unsigned short* qb = qbf + bh * SPAD * EOUT_;
  const unsigned short* kb = kbf + bh * SPAD * EOUT_;
  const unsigned short* vb = vT + bh * EOUT_ * SPAD;

  // ---- phase A: scores = (Q K^T)/16, bf16 into LDS ----
  bf16x8 aq0 = *(const bf16x8*)(qb + (size_t)(s0 + c) * EOUT_ + qd * 8);
  bf16x8 aq1 = *(const bf16x8*)(qb + (size_t)(s0 + c) * EOUT_ + 32 + qd * 8);
  for (int tt = wv_; tt < 63; tt += 4) {
    int t0 = tt * 16;
    f32x4 acc = {0.f, 0.f, 0.f, 0.f};
    const unsigned short* krow = kb + (size_t)(t0 + c) * EOUT_ + qd * 8;
    acc = __builtin_amdgcn_mfma_f32_16x16x32_bf16(aq0, *(const bf16x8*)krow, acc, 0, 0, 0);
    acc = __builtin_amdgcn_mfma_f32_16x16x32_bf16(aq1, *(const bf16x8*)(krow + 32), acc, 0, 0, 0);
#pragma unroll
    for (int i = 0; i < 4; ++i)
      sc[(qd * 4 + i) * SCW + t0 + c] = f2bf(acc[i] * 0.0625f);
  }
  // cols 1008..1023 never written by phase A: zero them (16 rows x 16 cols)
  sc[(tid >> 4) * SCW + 1008 + (tid & 15)] = 0;
  __syncthreads();

  // ---- phase B: row-per-wave, coalesced mask; l = exp(s)*mask, rs per row ----
#pragma unroll
  for (int rr = 0; rr < 4; ++rr) {
    int r = wv_ * 4 + rr;
    int srow = s0 + r;
    if (srow < S_) {
      const float* mrow = mpad + (size_t)srow * SPAD;
      float nacc = 0.0f;
#pragma unroll
      for (int ci = 0; ci < 4; ++ci) {
        int t0c = ci * 256 + 4 * l;
        bf16x4 sv = *(const bf16x4*)&sc[r * SCW + t0c];
        f32x4 mv = *(const f32x4*)(mrow + t0c);
        bf16x4 lvv;
#pragma unroll
        for (int j = 0; j < 4; ++j) {
          float e = __expf(bf2f((unsigned short)sv[j]));
          float lval = e * mv[j];  // mpad pad cols are 0 -> lval 0
          nacc += lval * lval;
          lvv[j] = (short)f2bf(lval);
        }
        *(bf16x4*)&sc[r * SCW + t0c] = lvv;
      }
      nacc += __shfl_xor(nacc, 1);
      nacc += __shfl_xor(nacc, 2);
      nacc += __shfl_xor(nacc, 4);
      nacc += __shfl_xor(nacc, 8);
      nacc += __shfl_xor(nacc, 16);
      nacc += __shfl_xor(nacc, 32);
      if (l == 0) rs[r] = 1.0f / fmaxf(sqrtf(nacc), 1e-12f);
    }
  }
  __syncthreads();

  if (tid < 16) rsbuf[((size_t)bh * 63 + tile) * 16 + tid] = rs[tid];

  // ---- phase D: out = (l V) * rs[row]; wave wv_ owns o in [16wv,16wv+16) ----
  f32x4 oacc = {0.f, 0.f, 0.f, 0.f};
  const unsigned short* vrow_ = vb + (size_t)(wv_ * 16 + c) * SPAD;
#pragma unroll
  for (int kstep = 0; kstep < 32; ++kstep) {
    bf16x8 afr = *(const bf16x8*)&sc[c * SCW + kstep * 32 + qd * 8];
    bf16x8 bfr = *(const bf16x8*)(vrow_ + kstep * 32 + qd * 8);
    oacc = __builtin_amdgcn_mfma_f32_16x16x32_bf16(afr, bfr, oacc, 0, 0, 0);
  }
#pragma unroll
  for (int i = 0; i < 4; ++i) {
    int row = qd * 4 + i;
    int srow = s0 + row;
    if (srow < S_)
      concat[((size_t)(b * S_) + srow) * NCOL + h * EOUT_ + wv_ * 16 + c] =
          oacc[i] * rs[row];
  }
}

// ---- kernel 5: wsum[b,s,t] = mask[s,t] * sum_h rs_h[s] * exp(score_h[s,t]) ----
// Recomputes QK^T per head (MFMA-cheap); exp + head-sum stay in C-layout regs.
__global__ __launch_bounds__(256) void wsum_kernel(
    const unsigned short* __restrict__ qbf, const unsigned short* __restrict__ kbf,
    const float* __restrict__ rsbuf, const float* __restrict__ mask,
    float* __restrict__ out) {
  __shared__ float wrs[H_ * 16];
  int tid = threadIdx.x;
  int wv_ = tid >> 6;
  int l = tid & 63;
  int qd = l >> 4;
  int c = l & 15;
  int bid = blockIdx.x;
  int tchunk = bid & 3;
  int rem = bid >> 2;
  int tile = rem % 63;
  int b = rem / 63;
  int s0 = tile * 16;
  int tb = tchunk * 256 + wv_ * 64;

  if (tid < H_ * 16) {
    int h = tid >> 4, row = tid & 15;
    wrs[tid] = rsbuf[((size_t)(b * H_ + h) * 63 + tile) * 16 + row];
  }
  __syncthreads();

  float wacc[16];
#pragma unroll
  for (int i = 0; i < 16; ++i) wacc[i] = 0.0f;

  for (int h = 0; h < H_; ++h) {
    size_t bh = (size_t)(b * H_ + h);
    const unsigned short* qb = qbf + bh * SPAD * EOUT_;
    const unsigned short* kb = kbf + bh * SPAD * EOUT_;
    bf16x8 aq0 = *(const bf16x8*)(qb + (size_t)(s0 + c) * EOUT_ + qd * 8);
    bf16x8 aq1 = *(const bf16x8*)(qb + (size_t)(s0 + c) * EOUT_ + 32 + qd * 8);
    f32x4 acc[4];
#pragma unroll
    for (int st = 0; st < 4; ++st) {
      const unsigned short* krow =
          kb + (size_t)(tb + st * 16 + c) * EOUT_ + qd * 8;
      f32x4 a = {0.f, 0.f, 0.f, 0.f};
      a = __builtin_amdgcn_mfma_f32_16x16x32_bf16(aq0, *(const bf16x8*)krow, a, 0, 0, 0);
      a = __builtin_amdgcn_mfma_f32_16x16x32_bf16(aq1, *(const bf16x8*)(krow + 32), a, 0, 0, 0);
      acc[st] = a;
    }
#pragma unroll
    for (int st = 0; st < 4; ++st)
#pragma unroll
      for (int i = 0; i < 4; ++i)
        wacc[st * 4 + i] += wrs[h * 16 + qd * 4 + i] * __expf(acc[st][i] * 0.0625f);
  }

  float* wsum = out + (size_t)B_ * S_ * NCOL;
#pragma unroll
  for (int st = 0; st < 4; ++st) {
    int t = tb + st * 16 + c;
#pragma unroll
    for (int i = 0; i < 4; ++i) {
      int srow = s0 + qd * 4 + i;
      if (srow < S_ && t < S_)
        wsum[((size_t)b * S_ + srow) * S_ + t] =
            wacc[st * 4 + i] * mask[(size_t)srow * S_ + t];
    }
  }
}

extern "C" void kernel_launch(void* const* d_in, const int* in_sizes, int n_in,
                              void* d_out, int out_size, void* d_ws, size_t ws_size,
                              hipStream_t stream) {
  const float* x = (const float*)d_in[0];
  const float* mask = (const float*)d_in[1];
  const float* Wq = (const float*)d_in[2];
  const float* bq = (const float*)d_in[3];
  const float* Wk = (const float*)d_in[4];
  const float* bk = (const float*)d_in[5];
  const float* Wv = (const float*)d_in[6];
  const float* bv = (const float*)d_in[7];
  float* out = (float*)d_out;

  char* ws = (char*)d_ws;
  const size_t NEED = 28308992;
  if (ws_size < NEED) return;  // fail cleanly rather than OOB
  unsigned short* xbf  = (unsigned short*)ws;              // 2,064,384 B
  unsigned short* wbf  = (unsigned short*)(ws + 2064384);  //   983,040 B
  unsigned short* qbf  = (unsigned short*)(ws + 3047424);  // 5,242,880 B
  unsigned short* kbf  = (unsigned short*)(ws + 8290304);  // 5,242,880 B
  unsigned short* vrow = (unsigned short*)(ws + 13533184); // 5,242,880 B
  unsigned short* vT   = (unsigned short*)(ws + 18776064); // 5,242,880 B
  float*          mpad = (float*)(ws + 24018944);          // 4,128,768 B
  float*          rsbuf = (float*)(ws + 28147712);         //   161,280 B

  convert_kernel<<<9984, 256, 0, stream>>>(x, Wq, Wk, Wv, mask, xbf, wbf, mpad);
  proj_kernel<<<1512, 256, 0, stream>>>(xbf, wbf, bq, bk, bv, qbf, kbf, vrow);
  transpose_v<<<640, 256, 0, stream>>>(vrow, vT);
  attn_kernel<<<2520, 256, 0, stream>>>(qbf, kbf, vT, mpad, rsbuf, out);
  wsum_kernel<<<1008, 256, 0, stream>>>(qbf, kbf, rsbuf, mask, out);
}